// Round 4
// baseline (97.034 us; speedup 1.0000x reference)
//
#include <hip/hip_runtime.h>
#include <hip/hip_bf16.h>
#include <math.h>

typedef __attribute__((ext_vector_type(8))) _Float16 half8;
typedef __attribute__((ext_vector_type(2))) _Float16 half2v;
typedef __attribute__((ext_vector_type(4))) float f32x4;
typedef __attribute__((ext_vector_type(4))) unsigned int u32x4;

#define NPT 1024
#define D   128
#define NT  64        // 16-row tiles
#define NPAIR 2080    // NT*(NT+1)/2

__device__ __forceinline__ unsigned int absdiff_pk(unsigned int a, unsigned int b) {
  half2v d = __builtin_bit_cast(half2v, a) - __builtin_bit_cast(half2v, b);
  return __builtin_bit_cast(unsigned int, d) & 0x7FFF7FFFu;
}

// ---------------- kernel 1: prep (xwg, xsw f16, w1p f16, zero outp/deg) -------
// xsw: swizzled f16 image of x: row i at byte i*256, elem k at ((2k)^((i&7)<<4))
// w1p: fragment-ordered f16 W1: frag f=(k>>3)*128+hid holds W1[k0..k0+7][hid]
__global__ __launch_bounds__(128) void k_prep(const float* __restrict__ x,
                                              const float* __restrict__ W1,
                                              const float* __restrict__ Wg,
                                              float* __restrict__ xwg,
                                              float* __restrict__ outp,
                                              float* __restrict__ deg,
                                              unsigned short* __restrict__ xsw,
                                              unsigned short* __restrict__ w1p) {
  __shared__ float xi[D];
  const int i = blockIdx.x;
  const int t = threadIdx.x;
  const float xv = x[i * D + t];
  xi[t] = xv;
  outp[i * D + t] = 0.f;
  if (t == 0) deg[i] = 0.f;
  const _Float16 hv = (_Float16)xv;
  const int byte = i * 256 + ((2 * t) ^ ((i & 7) << 4));
  *(unsigned short*)((unsigned char*)xsw + byte) =
      __builtin_bit_cast(unsigned short, hv);
  if (i < 128) {  // t = k index, i = hid
    const _Float16 wv = (_Float16)W1[t * 128 + i];
    w1p[((t >> 3) * 128 + i) * 8 + (t & 7)] = __builtin_bit_cast(unsigned short, wv);
  }
  __syncthreads();
  float acc = 0.f;
#pragma unroll 8
  for (int k = 0; k < D; ++k) acc += xi[k] * Wg[k * D + t];
  xwg[i * D + t] = acc;
}

// ---------------- kernel 2: symmetric tile-pair adjacency (f16 MFMA) ----------
// 2080 blocks x 256 thr (4 waves). Block = tile-pair (ti<=tj), 16i x 16j.
// Wave w: hid-half hh=w&1 (64 hid, W1 slice in 64 VGPR), i-parity ip=w>>1.
// No barriers in main loop; partial W2-dots combined via sP[2][16][16] LDS.
__global__ __launch_bounds__(256, 4) void k_adj(const unsigned short* __restrict__ xsw,
                                                const unsigned short* __restrict__ w1p,
                                                const float* __restrict__ b1,
                                                const float* __restrict__ W2,
                                                const float* __restrict__ b2,
                                                float* __restrict__ adj,
                                                float* __restrict__ deg) {
  __shared__ float sP[2][16][16];
  __shared__ float degJ[16];

  const int tid  = threadIdx.x;
  const int lane = tid & 63;
  const int w    = tid >> 6;     // 0..3
  const int l15  = lane & 15;
  const int g    = lane >> 4;    // 0..3 (k-group)
  const int hh   = w & 1;        // hid half
  const int ip   = w >> 1;       // i parity

  // triangular decode: blockIdx -> (ti, tj), ti <= tj
  int b = blockIdx.x, ti = 0;
  while (b >= NT - ti) { b -= NT - ti; ++ti; }
  const int tj = ti + b;

  if (tid < 16) degJ[tid] = 0.f;

  // W1 slice -> registers: bf[ks][ht2], hid = hh*64 + ht2*16 + l15, k=ks*32+g*8+e
  half8 bf[4][4];
#pragma unroll
  for (int ks = 0; ks < 4; ++ks)
#pragma unroll
    for (int ht2 = 0; ht2 < 4; ++ht2)
      bf[ks][ht2] = *(const half8*)(w1p +
          ((ks * 4 + g) * 128 + hh * 64 + ht2 * 16 + l15) * 8);

  float b1v[4], w2v[4];
#pragma unroll
  for (int ht2 = 0; ht2 < 4; ++ht2) {
    const int hid = hh * 64 + ht2 * 16 + l15;
    b1v[ht2] = b1[hid];
    w2v[ht2] = W2[hid];
  }

  const unsigned char* xs = (const unsigned char*)xsw;
  const unsigned char* xj = xs + (tj * 16 + l15) * 256;  // per-lane j-row
  const int sxJ = (l15 & 7) << 4;  // (tj*16+l15)&7 == l15&7

#pragma unroll 1
  for (int st = 0; st < 8; ++st) {
    const int iloc = st * 2 + ip;
    const int gi = ti * 16 + iloc;
    const unsigned char* xi = xs + gi * 256;
    const int sxI = (gi & 7) << 4;

    f32x4 acc[4];
#pragma unroll
    for (int ht2 = 0; ht2 < 4; ++ht2)
      acc[ht2] = f32x4{b1v[ht2], b1v[ht2], b1v[ht2], b1v[ht2]};

#pragma unroll
    for (int ks = 0; ks < 4; ++ks) {
      const int k0b = ks * 64 + g * 16;  // byte offset of 2*k0
      const u32x4 xiu = *(const u32x4*)(xi + (k0b ^ sxI));
      const u32x4 jru = *(const u32x4*)(xj + (k0b ^ sxJ));
      u32x4 afu;
#pragma unroll
      for (int p = 0; p < 4; ++p) afu[p] = absdiff_pk(jru[p], xiu[p]);
      const half8 af = __builtin_bit_cast(half8, afu);
#pragma unroll
      for (int ht2 = 0; ht2 < 4; ++ht2)
        acc[ht2] = __builtin_amdgcn_mfma_f32_16x16x32_f16(af, bf[ks][ht2],
                                                          acc[ht2], 0, 0, 0);
    }
    // partial W2 dot over this wave's 64 hid
    float s0 = 0.f, s1 = 0.f, s2 = 0.f, s3 = 0.f;
#pragma unroll
    for (int ht2 = 0; ht2 < 4; ++ht2) {
      s0 += fmaxf(acc[ht2][0], 0.f) * w2v[ht2];
      s1 += fmaxf(acc[ht2][1], 0.f) * w2v[ht2];
      s2 += fmaxf(acc[ht2][2], 0.f) * w2v[ht2];
      s3 += fmaxf(acc[ht2][3], 0.f) * w2v[ht2];
    }
#pragma unroll
    for (int m = 1; m <= 8; m <<= 1) {
      s0 += __shfl_xor(s0, m);
      s1 += __shfl_xor(s1, m);
      s2 += __shfl_xor(s2, m);
      s3 += __shfl_xor(s3, m);
    }
    if (l15 == 0) {  // j = g*4 + r
      f32x4 stv{s0, s1, s2, s3};
      *(f32x4*)&sP[hh][iloc][g * 4] = stv;
    }
  }
  __syncthreads();

  // final pass: 256 threads, one (i,j) each
  const int i = tid >> 4, j = tid & 15;
  const int gi = ti * 16 + i, gj = tj * 16 + j;
  const float sv = sP[0][i][j] + sP[1][i][j] + b2[0];
  const float sig = 1.f / (1.f + __expf(-sv));
  adj[gi * NPT + gj] = sig;
  // rowsum -> deg[gi]
  float rs = sig;
#pragma unroll
  for (int m = 1; m <= 8; m <<= 1) rs += __shfl_xor(rs, m);
  if (j == 0) atomicAdd(&deg[gi], rs);
  if (ti != tj) {
    adj[gj * NPT + gi] = sig;  // mirror
    float cs = sig;            // colsum partial over this wave's 4 i
    cs += __shfl_xor(cs, 16);
    cs += __shfl_xor(cs, 32);
    if (lane < 16) atomicAdd(&degJ[j], cs);
  }
  __syncthreads();
  if (tid < 16 && ti != tj) atomicAdd(&deg[tj * 16 + tid], degJ[tid]);
}

// ---------------- kernel 3: partial = sum_j (adj*dinv_j) * xwg, atomic --------
__global__ __launch_bounds__(256) void k_d1(const float* __restrict__ adj,
                                            const float* __restrict__ xwg,
                                            const float* __restrict__ deg,
                                            float* __restrict__ outp) {
  __shared__ float ysh[64 * 128];
  __shared__ float anT[64 * 36];
  const int tid = threadIdx.x;
  const int i0 = blockIdx.x * 32;
  const int jb = blockIdx.y * 64;
  const int iq = tid >> 5;
  const int tq = tid & 31;
  float acc[4][4];
#pragma unroll
  for (int a = 0; a < 4; ++a)
#pragma unroll
    for (int c = 0; c < 4; ++c) acc[a][c] = 0.f;

#pragma unroll
  for (int it = 0; it < 8; ++it) {
    const int rw = it * 8 + (tid >> 5);
    const int cl = (tid & 31) * 4;
    *(f32x4*)&ysh[rw * 128 + cl] = *(const f32x4*)&xwg[(jb + rw) * 128 + cl];
  }
  const float dj = rsqrtf(deg[jb + (tid & 63)]);
#pragma unroll
  for (int it = 0; it < 8; ++it) {
    const int ii = it * 4 + (tid >> 6);
    const int jj = tid & 63;
    anT[jj * 36 + ii] = adj[(i0 + ii) * NPT + jb + jj] * dj;
  }
  __syncthreads();
#pragma unroll 4
  for (int jj = 0; jj < 64; ++jj) {
    const f32x4 yv = *(const f32x4*)&ysh[jj * 128 + tq * 4];
    const f32x4 an4 = *(const f32x4*)&anT[jj * 36 + iq * 4];
#pragma unroll
    for (int a = 0; a < 4; ++a)
#pragma unroll
      for (int c = 0; c < 4; ++c) acc[a][c] += an4[a] * yv[c];
  }
#pragma unroll
  for (int a = 0; a < 4; ++a)
#pragma unroll
    for (int c = 0; c < 4; ++c)
      atomicAdd(&outp[(i0 + iq * 4 + a) * D + tq * 4 + c], acc[a][c]);
}

// ---------------- kernel 4: out = leaky(rsqrt(deg_i) * partial + bg) ----------
__global__ void k_d2(float* __restrict__ outp, const float* __restrict__ deg,
                     const float* __restrict__ bg) {
  const int idx = blockIdx.x * 256 + threadIdx.x;
  const int i = idx >> 7, t = idx & 127;
  const float v = outp[idx] * rsqrtf(deg[i]) + bg[t];
  outp[idx] = v > 0.f ? v : 0.2f * v;
}

extern "C" void kernel_launch(void* const* d_in, const int* in_sizes, int n_in,
                              void* d_out, int out_size, void* d_ws, size_t ws_size,
                              hipStream_t stream) {
  const float* x  = (const float*)d_in[0];
  const float* W1 = (const float*)d_in[1];
  const float* b1 = (const float*)d_in[2];
  const float* W2 = (const float*)d_in[3];
  const float* b2 = (const float*)d_in[4];
  const float* Wg = (const float*)d_in[5];
  const float* bg = (const float*)d_in[6];

  float* outp = (float*)d_out;              // [1024*128]
  float* adj  = outp + NPT * D;             // [1024*1024]
  float* xwg  = (float*)d_ws;               // [1024*128] f32
  float* deg  = xwg + NPT * D;              // [1024] f32
  unsigned short* xsw = (unsigned short*)(deg + NPT);  // [1024*128] f16 swizzled
  unsigned short* w1p = xsw + NPT * D;                 // [128*128] f16 frag-ordered

  k_prep<<<NPT, 128, 0, stream>>>(x, W1, Wg, xwg, outp, deg, xsw, w1p);
  k_adj<<<NPAIR, 256, 0, stream>>>(xsw, w1p, b1, W2, b2, adj, deg);
  k_d1<<<dim3(32, 16), 256, 0, stream>>>(adj, xwg, deg, outp);
  k_d2<<<512, 256, 0, stream>>>(outp, deg, bg);
}

// Round 5
// 76.261 us; speedup vs baseline: 1.2724x; 1.2724x over previous
//
#include <hip/hip_runtime.h>
#include <hip/hip_bf16.h>
#include <math.h>

typedef __attribute__((ext_vector_type(8))) _Float16 half8;
typedef __attribute__((ext_vector_type(2))) _Float16 half2v;
typedef __attribute__((ext_vector_type(4))) float f32x4;
typedef __attribute__((ext_vector_type(4))) unsigned int u32x4;

#define NPT 1024
#define D   128

__device__ __forceinline__ unsigned int absdiff_pk(unsigned int a, unsigned int b) {
  half2v d = __builtin_bit_cast(half2v, a) - __builtin_bit_cast(half2v, b);
  return __builtin_bit_cast(unsigned int, d) & 0x7FFF7FFFu;
}

// async global->LDS, 16B per lane; lds base wave-uniform, global addr per-lane
__device__ __forceinline__ void gload_lds16(const void* g, void* l) {
  __builtin_amdgcn_global_load_lds(
      (const __attribute__((address_space(1))) void*)g,
      (__attribute__((address_space(3))) void*)l, 16, 0, 0);
}

// ---------------- kernel 1: prep ----------------
// xsw: swizzled f16 x: row i base i*256B, elem k at ((2k)^((i&7)<<4))
// w1p: fragment-ordered f16 W1: w1p[((k>>3)*128+hid)*8 + (k&7)] = W1[k][hid]
// xwghT: f16 [128 t][1024 i] transpose of x@Wg
__global__ __launch_bounds__(128) void k_prep(const float* __restrict__ x,
                                              const float* __restrict__ W1,
                                              const float* __restrict__ Wg,
                                              float* __restrict__ outp,
                                              float* __restrict__ deg,
                                              unsigned short* __restrict__ xsw,
                                              unsigned short* __restrict__ w1p,
                                              unsigned short* __restrict__ xwghT) {
  __shared__ float xi[D];
  const int i = blockIdx.x;
  const int t = threadIdx.x;
  const float xv = x[i * D + t];
  xi[t] = xv;
  outp[i * D + t] = 0.f;
  if (t == 0) deg[i] = 0.f;
  const _Float16 hv = (_Float16)xv;
  const int byte = i * 256 + ((2 * t) ^ ((i & 7) << 4));
  *(unsigned short*)((unsigned char*)xsw + byte) =
      __builtin_bit_cast(unsigned short, hv);
  if (i < 128) {  // t = k, i = hid
    const _Float16 wv = (_Float16)W1[t * 128 + i];
    w1p[((t >> 3) * 128 + i) * 8 + (t & 7)] = __builtin_bit_cast(unsigned short, wv);
  }
  __syncthreads();
  float acc = 0.f;
#pragma unroll 8
  for (int k = 0; k < D; ++k) acc += xi[k] * Wg[k * D + t];
  const _Float16 av = (_Float16)acc;
  xwghT[t * NPT + i] = __builtin_bit_cast(unsigned short, av);
}

// ---------------- kernel 2: adjacency, D[m=hid][n=j] ----------------
// grid (512,2) x 256 thr (4 waves). Block: 2 i-rows x 512 j (16 chunks of 32).
// Wave w: hh=w&1 (64-hid half, W1 in 64 VGPR), iloc=w>>1.
// A = W1 (static regs), B = |xi - xj| built from LDS chunk. One barrier/chunk.
__global__ __launch_bounds__(256, 3) void k_adj(const unsigned short* __restrict__ xsw,
                                                const unsigned short* __restrict__ w1p,
                                                const float* __restrict__ b1,
                                                const float* __restrict__ W2,
                                                const float* __restrict__ b2,
                                                float* __restrict__ adj,
                                                float* __restrict__ deg) {
  __shared__ __align__(16) unsigned char xb[2][8192];
  __shared__ float sP[2][2][2][32];  // [parity][hh][iloc][j]

  const int tid  = threadIdx.x;
  const int lane = tid & 63;
  const int w    = tid >> 6;   // 0..3
  const int l15  = lane & 15;
  const int g    = lane >> 4;  // 0..3
  const int hh   = w & 1;
  const int iloc = w >> 1;
  const int ibase = blockIdx.x * 2;
  const int jb    = blockIdx.y * 512;

  // W1 slice -> regs: A[m=hid][k], hid = hh*64+ht2*16+l15, k = ks*32+g*8+e
  half8 w1f[4][4];
#pragma unroll
  for (int ks = 0; ks < 4; ++ks)
#pragma unroll
    for (int ht2 = 0; ht2 < 4; ++ht2)
      w1f[ks][ht2] = *(const half8*)(w1p +
          ((ks * 4 + g) * 128 + hh * 64 + ht2 * 16 + l15) * 8);

  f32x4 b1v[4], w2v[4];
#pragma unroll
  for (int ht2 = 0; ht2 < 4; ++ht2) {
    b1v[ht2] = *(const f32x4*)&b1[hh * 64 + ht2 * 16 + g * 4];
    w2v[ht2] = *(const f32x4*)&W2[hh * 64 + ht2 * 16 + g * 4];
  }
  const float b2s = b2[0];

  // xi pk fragments (this wave's single i-row), broadcast loads
  const int gi = ibase + iloc;
  const unsigned char* xrow = (const unsigned char*)xsw + gi * 256;
  const int sxI = (gi & 7) << 4;
  u32x4 xiu[4];
#pragma unroll
  for (int ks = 0; ks < 4; ++ks)
    xiu[ks] = *(const u32x4*)(xrow + ((ks * 64 + g * 16) ^ sxI));

  const unsigned char* xsb = (const unsigned char*)xsw;
  auto stage = [&](int c) {
    const int cb = (jb + c * 32) * 256;
    gload_lds16(xsb + cb + w * 2048 + lane * 16, xb[c & 1] + w * 2048);
    gload_lds16(xsb + cb + w * 2048 + 1024 + lane * 16, xb[c & 1] + w * 2048 + 1024);
  };

  stage(0);
  stage(1);
  __syncthreads();

  const int sxJ = (l15 & 7) << 4;
#pragma unroll 1
  for (int c = 0; c < 16; ++c) {
    const unsigned char* cur = xb[c & 1];
    float sj[2];
#pragma unroll
    for (int jsub = 0; jsub < 2; ++jsub) {
      f32x4 acc[4];
#pragma unroll
      for (int ht2 = 0; ht2 < 4; ++ht2) acc[ht2] = b1v[ht2];
#pragma unroll
      for (int ks = 0; ks < 4; ++ks) {
        const u32x4 jr = *(const u32x4*)(cur + (jsub * 16 + l15) * 256 +
                                         ((ks * 64 + g * 16) ^ sxJ));
        u32x4 afu;
#pragma unroll
        for (int p = 0; p < 4; ++p) afu[p] = absdiff_pk(jr[p], xiu[ks][p]);
        const half8 af = __builtin_bit_cast(half8, afu);
#pragma unroll
        for (int ht2 = 0; ht2 < 4; ++ht2)
          acc[ht2] = __builtin_amdgcn_mfma_f32_16x16x32_f16(w1f[ks][ht2], af,
                                                            acc[ht2], 0, 0, 0);
      }
      // per-lane W2 dot over this lane's 16 hid (ht2 x r), then 4-lane g-reduce
      float s = 0.f;
#pragma unroll
      for (int ht2 = 0; ht2 < 4; ++ht2)
#pragma unroll
        for (int r = 0; r < 4; ++r)
          s += fmaxf(acc[ht2][r], 0.f) * w2v[ht2][r];
      s += __shfl_xor(s, 16);
      s += __shfl_xor(s, 32);
      sj[jsub] = s;
    }
    if (lane < 16) {
      sP[c & 1][hh][iloc][l15] = sj[0];
      sP[c & 1][hh][iloc][16 + l15] = sj[1];
    }
    __syncthreads();  // sP visible; chunk c reads done; c+1 staging drained
    if (c + 2 < 16) stage(c + 2);
    if (w == 0) {  // phase B: 64 outputs
      const int il = lane >> 5, j = lane & 31;
      const float sv = sP[c & 1][0][il][j] + sP[c & 1][1][il][j] + b2s;
      const float sig = 1.f / (1.f + __expf(-sv));
      adj[(ibase + il) * NPT + jb + c * 32 + j] = sig;
      float rs = sig;
#pragma unroll
      for (int m = 1; m <= 16; m <<= 1) rs += __shfl_xor(rs, m);
      if (j == 0) atomicAdd(&deg[ibase + il], rs);
    }
  }
}

// ---------------- kernel 3: out-partial via f16 MFMA, D[m=t][n=i] ----------
// out[t][i] += sum_j xwghT[t][j] * (adj[i][j]*dinv_j)   (adj symmetric)
// grid (64,4) x 256 thr. Block: 16 i x 128 t x 256 j. Wave w: t-tiles {2w,2w+1}.
__global__ __launch_bounds__(256) void k_d1(const float* __restrict__ adj,
                                            const unsigned short* __restrict__ xwghT,
                                            const float* __restrict__ deg,
                                            float* __restrict__ outp) {
  __shared__ unsigned short dv[256];
  const int tid  = threadIdx.x;
  const int lane = tid & 63;
  const int w    = tid >> 6;
  const int l15  = lane & 15;
  const int g    = lane >> 4;
  const int i0 = blockIdx.x * 16;
  const int jb = blockIdx.y * 256;

  const _Float16 dh = (_Float16)rsqrtf(deg[jb + tid]);
  dv[tid] = __builtin_bit_cast(unsigned short, dh);
  __syncthreads();

  f32x4 acc[2] = {f32x4{0,0,0,0}, f32x4{0,0,0,0}};
#pragma unroll
  for (int ks = 0; ks < 8; ++ks) {
    const int kofs = ks * 32 + g * 8;
    const f32x4 av0 = *(const f32x4*)&adj[(i0 + l15) * NPT + jb + kofs];
    const f32x4 av1 = *(const f32x4*)&adj[(i0 + l15) * NPT + jb + kofs + 4];
    const half2v* dq = (const half2v*)&dv[kofs];
    u32x4 bu;
    bu[0] = __builtin_bit_cast(unsigned int,
        half2v(__builtin_bit_cast(half2v, __builtin_amdgcn_cvt_pkrtz(av0[0], av0[1])) * dq[0]));
    bu[1] = __builtin_bit_cast(unsigned int,
        half2v(__builtin_bit_cast(half2v, __builtin_amdgcn_cvt_pkrtz(av0[2], av0[3])) * dq[1]));
    bu[2] = __builtin_bit_cast(unsigned int,
        half2v(__builtin_bit_cast(half2v, __builtin_amdgcn_cvt_pkrtz(av1[0], av1[1])) * dq[2]));
    bu[3] = __builtin_bit_cast(unsigned int,
        half2v(__builtin_bit_cast(half2v, __builtin_amdgcn_cvt_pkrtz(av1[2], av1[3])) * dq[3]));
    const half8 bf = __builtin_bit_cast(half8, bu);
#pragma unroll
    for (int tt = 0; tt < 2; ++tt) {
      const int trow = w * 32 + tt * 16 + l15;
      const half8 af = *(const half8*)(xwghT + trow * NPT + jb + kofs);
      acc[tt] = __builtin_amdgcn_mfma_f32_16x16x32_f16(af, bf, acc[tt], 0, 0, 0);
    }
  }
#pragma unroll
  for (int tt = 0; tt < 2; ++tt)
#pragma unroll
    for (int r = 0; r < 4; ++r)
      atomicAdd(&outp[(i0 + l15) * D + w * 32 + tt * 16 + g * 4 + r], acc[tt][r]);
}

// ---------------- kernel 4: out = leaky(rsqrt(deg_i) * partial + bg) --------
__global__ void k_d2(float* __restrict__ outp, const float* __restrict__ deg,
                     const float* __restrict__ bg) {
  const int idx = blockIdx.x * 256 + threadIdx.x;
  const int i = idx >> 7, t = idx & 127;
  const float v = outp[idx] * rsqrtf(deg[i]) + bg[t];
  outp[idx] = v > 0.f ? v : 0.2f * v;
}

extern "C" void kernel_launch(void* const* d_in, const int* in_sizes, int n_in,
                              void* d_out, int out_size, void* d_ws, size_t ws_size,
                              hipStream_t stream) {
  const float* x  = (const float*)d_in[0];
  const float* W1 = (const float*)d_in[1];
  const float* b1 = (const float*)d_in[2];
  const float* W2 = (const float*)d_in[3];
  const float* b2 = (const float*)d_in[4];
  const float* Wg = (const float*)d_in[5];
  const float* bg = (const float*)d_in[6];

  float* outp = (float*)d_out;              // [1024*128]
  float* adj  = outp + NPT * D;             // [1024*1024]
  float* deg  = (float*)d_ws;               // [1024] f32
  unsigned short* xsw   = (unsigned short*)(deg + NPT);  // [1024*128] f16 swizzled
  unsigned short* w1p   = xsw + NPT * D;                 // [128*128] f16 frag-ordered
  unsigned short* xwghT = w1p + D * D;                   // [128*1024] f16

  k_prep<<<NPT, 128, 0, stream>>>(x, W1, Wg, outp, deg, xsw, w1p, xwghT);
  k_adj<<<dim3(512, 2), 256, 0, stream>>>(xsw, w1p, b1, W2, b2, adj, deg);
  k_d1<<<dim3(64, 4), 256, 0, stream>>>(adj, xwghT, deg, outp);
  k_d2<<<512, 256, 0, stream>>>(outp, deg, bg);
}

// Round 6
// 72.658 us; speedup vs baseline: 1.3355x; 1.0496x over previous
//
#include <hip/hip_runtime.h>
#include <hip/hip_bf16.h>
#include <math.h>

typedef __attribute__((ext_vector_type(8))) _Float16 half8;
typedef __attribute__((ext_vector_type(2))) _Float16 half2v;
typedef __attribute__((ext_vector_type(4))) float f32x4;
typedef __attribute__((ext_vector_type(4))) unsigned int u32x4;

#define NPT 1024
#define D   128

__device__ __forceinline__ unsigned int absdiff_pk(unsigned int a, unsigned int b) {
  half2v d = __builtin_bit_cast(half2v, a) - __builtin_bit_cast(half2v, b);
  return __builtin_bit_cast(unsigned int, d) & 0x7FFF7FFFu;
}

__device__ __forceinline__ unsigned int pk_max(unsigned int a, unsigned int b) {
  unsigned int r;
  asm("v_pk_max_f16 %0, %1, %2" : "=v"(r) : "v"(a), "v"(b));
  return r;
}

__device__ __forceinline__ unsigned int pkrtz(float lo, float hi) {
  return __builtin_bit_cast(unsigned int, __builtin_amdgcn_cvt_pkrtz(lo, hi));
}

__device__ __forceinline__ float fdot2(unsigned int a, unsigned int b, float c) {
  return __builtin_amdgcn_fdot2(__builtin_bit_cast(half2v, a),
                                __builtin_bit_cast(half2v, b), c, false);
}

// ---------------- kernel 1: prep ----------------
// xsw: swizzled f16 x: row i base i*256B, elem k at ((2k)^((i&7)<<4))
// w1p: fragment-ordered f16 W1: w1p[((k>>3)*128+hid)*8 + (k&7)] = W1[k][hid]
// xwghT: f16 [128 t][1024 i] transpose of x@Wg
__global__ __launch_bounds__(128) void k_prep(const float* __restrict__ x,
                                              const float* __restrict__ W1,
                                              const float* __restrict__ Wg,
                                              float* __restrict__ outp,
                                              float* __restrict__ deg,
                                              unsigned short* __restrict__ xsw,
                                              unsigned short* __restrict__ w1p,
                                              unsigned short* __restrict__ xwghT) {
  __shared__ float xi[D];
  const int i = blockIdx.x;
  const int t = threadIdx.x;
  const float xv = x[i * D + t];
  xi[t] = xv;
  outp[i * D + t] = 0.f;
  if (t == 0) deg[i] = 0.f;
  const _Float16 hv = (_Float16)xv;
  const int byte = i * 256 + ((2 * t) ^ ((i & 7) << 4));
  *(unsigned short*)((unsigned char*)xsw + byte) =
      __builtin_bit_cast(unsigned short, hv);
  if (i < 128) {  // t = k, i = hid
    const _Float16 wv = (_Float16)W1[t * 128 + i];
    w1p[((t >> 3) * 128 + i) * 8 + (t & 7)] = __builtin_bit_cast(unsigned short, wv);
  }
  __syncthreads();
  float acc = 0.f;
#pragma unroll 8
  for (int k = 0; k < D; ++k) acc += xi[k] * Wg[k * D + t];
  const _Float16 av = (_Float16)acc;
  xwghT[t * NPT + i] = __builtin_bit_cast(unsigned short, av);
}

// ---------------- kernel 2: adjacency, D[m=hid][n=j], no LDS, no barriers ----
// grid (256,4) x 256 thr. Wave = 1 i-row x 256 j (16 groups of 16).
// Full 128-hid W1 slice per wave in 128 VGPR; j fragments per-lane from global.
__global__ __launch_bounds__(256, 2) void k_adj(const unsigned short* __restrict__ xsw,
                                                const unsigned short* __restrict__ w1p,
                                                const float* __restrict__ b1,
                                                const float* __restrict__ W2,
                                                const float* __restrict__ b2,
                                                float* __restrict__ adj,
                                                float* __restrict__ deg) {
  const int tid  = threadIdx.x;
  const int lane = tid & 63;
  const int w    = tid >> 6;   // 0..3
  const int l15  = lane & 15;
  const int g    = lane >> 4;  // 0..3
  const int i  = blockIdx.x * 4 + w;
  const int jq = blockIdx.y;   // 0..3, 256 j each

  // W1 -> regs: A[m=hid][k], hid = ht*16+l15, k = ks*32+g*8+e
  half8 w1f[4][8];
#pragma unroll
  for (int ks = 0; ks < 4; ++ks)
#pragma unroll
    for (int ht = 0; ht < 8; ++ht)
      w1f[ks][ht] = *(const half8*)(w1p + ((ks * 4 + g) * 128 + ht * 16 + l15) * 8);

  // relu(a+b1)*w2 = max(a,-b1)*w2 + b1*w2 : pack -b1, w2 as f16x2; c0 = sum b1*w2
  unsigned int nb1pk[8][2], w2pk[8][2];
  float c0 = 0.f;
#pragma unroll
  for (int ht = 0; ht < 8; ++ht) {
    const f32x4 bv = *(const f32x4*)&b1[ht * 16 + g * 4];
    const f32x4 wv = *(const f32x4*)&W2[ht * 16 + g * 4];
    c0 += bv[0] * wv[0] + bv[1] * wv[1] + bv[2] * wv[2] + bv[3] * wv[3];
    nb1pk[ht][0] = pkrtz(-bv[0], -bv[1]);
    nb1pk[ht][1] = pkrtz(-bv[2], -bv[3]);
    w2pk[ht][0] = pkrtz(wv[0], wv[1]);
    w2pk[ht][1] = pkrtz(wv[2], wv[3]);
  }
  c0 += __shfl_xor(c0, 16);
  c0 += __shfl_xor(c0, 32);
  const float B2 = b2[0] + c0;

  // xi fragments (broadcast row i)
  const unsigned char* xsb = (const unsigned char*)xsw;
  const unsigned char* xrow = xsb + i * 256;
  const int sxI = (i & 7) << 4;
  u32x4 xiu[4];
#pragma unroll
  for (int ks = 0; ks < 4; ++ks)
    xiu[ks] = *(const u32x4*)(xrow + ((ks * 64 + g * 16) ^ sxI));

  // per-lane j-row base: row = jq*256 + grp*16 + l15; (row&7)==(l15&7)
  const int sxJ = (l15 & 7) << 4;
  const unsigned char* jrow = xsb + (jq * 256 + l15) * 256;
  const int k0b = (0 * 64 + g * 16) ^ sxJ;
  const int k1b = (1 * 64 + g * 16) ^ sxJ;
  const int k2b = (2 * 64 + g * 16) ^ sxJ;
  const int k3b = (3 * 64 + g * 16) ^ sxJ;

  u32x4 jr0 = *(const u32x4*)(jrow + k0b);
  u32x4 jr1 = *(const u32x4*)(jrow + k1b);
  u32x4 jr2 = *(const u32x4*)(jrow + k2b);
  u32x4 jr3 = *(const u32x4*)(jrow + k3b);

  float degacc = 0.f;
#pragma unroll 1
  for (int grp = 0; grp < 16; ++grp) {
    const unsigned char* nrow = jrow + (grp + 1) * 4096;
    f32x4 acc[8];
#pragma unroll
    for (int ht = 0; ht < 8; ++ht) acc[ht] = f32x4{0.f, 0.f, 0.f, 0.f};

    // ks = 0
    {
      u32x4 afu;
#pragma unroll
      for (int p = 0; p < 4; ++p) afu[p] = absdiff_pk(jr0[p], xiu[0][p]);
      if (grp < 15) jr0 = *(const u32x4*)(nrow + k0b);
      const half8 af = __builtin_bit_cast(half8, afu);
#pragma unroll
      for (int ht = 0; ht < 8; ++ht)
        acc[ht] = __builtin_amdgcn_mfma_f32_16x16x32_f16(w1f[0][ht], af, acc[ht], 0, 0, 0);
    }
    // ks = 1
    {
      u32x4 afu;
#pragma unroll
      for (int p = 0; p < 4; ++p) afu[p] = absdiff_pk(jr1[p], xiu[1][p]);
      if (grp < 15) jr1 = *(const u32x4*)(nrow + k1b);
      const half8 af = __builtin_bit_cast(half8, afu);
#pragma unroll
      for (int ht = 0; ht < 8; ++ht)
        acc[ht] = __builtin_amdgcn_mfma_f32_16x16x32_f16(w1f[1][ht], af, acc[ht], 0, 0, 0);
    }
    // ks = 2
    {
      u32x4 afu;
#pragma unroll
      for (int p = 0; p < 4; ++p) afu[p] = absdiff_pk(jr2[p], xiu[2][p]);
      if (grp < 15) jr2 = *(const u32x4*)(nrow + k2b);
      const half8 af = __builtin_bit_cast(half8, afu);
#pragma unroll
      for (int ht = 0; ht < 8; ++ht)
        acc[ht] = __builtin_amdgcn_mfma_f32_16x16x32_f16(w1f[2][ht], af, acc[ht], 0, 0, 0);
    }
    // ks = 3
    {
      u32x4 afu;
#pragma unroll
      for (int p = 0; p < 4; ++p) afu[p] = absdiff_pk(jr3[p], xiu[3][p]);
      if (grp < 15) jr3 = *(const u32x4*)(nrow + k3b);
      const half8 af = __builtin_bit_cast(half8, afu);
#pragma unroll
      for (int ht = 0; ht < 8; ++ht)
        acc[ht] = __builtin_amdgcn_mfma_f32_16x16x32_f16(w1f[3][ht], af, acc[ht], 0, 0, 0);
    }

    // dot: s = sum_h max(acc,-b1)*w2  (f16 pk), + B2 later
    float s = 0.f;
#pragma unroll
    for (int ht = 0; ht < 8; ++ht) {
      unsigned int h0 = pk_max(pkrtz(acc[ht][0], acc[ht][1]), nb1pk[ht][0]);
      s = fdot2(h0, w2pk[ht][0], s);
      unsigned int h1 = pk_max(pkrtz(acc[ht][2], acc[ht][3]), nb1pk[ht][1]);
      s = fdot2(h1, w2pk[ht][1], s);
    }
    s += __shfl_xor(s, 16);
    s += __shfl_xor(s, 32);
    if (lane < 16) {
      const float sig = 1.f / (1.f + __expf(-(s + B2)));
      adj[i * NPT + jq * 256 + grp * 16 + l15] = sig;
      degacc += sig;
    }
  }
  if (lane < 16) {
#pragma unroll
    for (int m = 1; m <= 8; m <<= 1) degacc += __shfl_xor(degacc, m);
    if (l15 == 0) atomicAdd(&deg[i], degacc);
  }
}

// ---------------- kernel 3: out-partial via f16 MFMA, D[m=t][n=i] ----------
// out[t][i] += sum_j xwghT[t][j] * (adj[i][j]*dinv_j)   (adj symmetric)
__global__ __launch_bounds__(256) void k_d1(const float* __restrict__ adj,
                                            const unsigned short* __restrict__ xwghT,
                                            const float* __restrict__ deg,
                                            float* __restrict__ outp) {
  __shared__ unsigned short dv[256];
  const int tid  = threadIdx.x;
  const int lane = tid & 63;
  const int w    = tid >> 6;
  const int l15  = lane & 15;
  const int g    = lane >> 4;
  const int i0 = blockIdx.x * 16;
  const int jb = blockIdx.y * 256;

  const _Float16 dh = (_Float16)rsqrtf(deg[jb + tid]);
  dv[tid] = __builtin_bit_cast(unsigned short, dh);
  __syncthreads();

  f32x4 acc[2] = {f32x4{0,0,0,0}, f32x4{0,0,0,0}};
#pragma unroll
  for (int ks = 0; ks < 8; ++ks) {
    const int kofs = ks * 32 + g * 8;
    const f32x4 av0 = *(const f32x4*)&adj[(i0 + l15) * NPT + jb + kofs];
    const f32x4 av1 = *(const f32x4*)&adj[(i0 + l15) * NPT + jb + kofs + 4];
    const half2v* dq = (const half2v*)&dv[kofs];
    u32x4 bu;
    bu[0] = __builtin_bit_cast(unsigned int,
        half2v(__builtin_bit_cast(half2v, __builtin_amdgcn_cvt_pkrtz(av0[0], av0[1])) * dq[0]));
    bu[1] = __builtin_bit_cast(unsigned int,
        half2v(__builtin_bit_cast(half2v, __builtin_amdgcn_cvt_pkrtz(av0[2], av0[3])) * dq[1]));
    bu[2] = __builtin_bit_cast(unsigned int,
        half2v(__builtin_bit_cast(half2v, __builtin_amdgcn_cvt_pkrtz(av1[0], av1[1])) * dq[2]));
    bu[3] = __builtin_bit_cast(unsigned int,
        half2v(__builtin_bit_cast(half2v, __builtin_amdgcn_cvt_pkrtz(av1[2], av1[3])) * dq[3]));
    const half8 bf = __builtin_bit_cast(half8, bu);
#pragma unroll
    for (int tt = 0; tt < 2; ++tt) {
      const int trow = w * 32 + tt * 16 + l15;
      const half8 af = *(const half8*)(xwghT + trow * NPT + jb + kofs);
      acc[tt] = __builtin_amdgcn_mfma_f32_16x16x32_f16(af, bf, acc[tt], 0, 0, 0);
    }
  }
#pragma unroll
  for (int tt = 0; tt < 2; ++tt)
#pragma unroll
    for (int r = 0; r < 4; ++r)
      atomicAdd(&outp[(i0 + l15) * D + w * 32 + tt * 16 + g * 4 + r], acc[tt][r]);
}

// ---------------- kernel 4: out = leaky(rsqrt(deg_i) * partial + bg) --------
__global__ void k_d2(float* __restrict__ outp, const float* __restrict__ deg,
                     const float* __restrict__ bg) {
  const int idx = blockIdx.x * 256 + threadIdx.x;
  const int i = idx >> 7, t = idx & 127;
  const float v = outp[idx] * rsqrtf(deg[i]) + bg[t];
  outp[idx] = v > 0.f ? v : 0.2f * v;
}

extern "C" void kernel_launch(void* const* d_in, const int* in_sizes, int n_in,
                              void* d_out, int out_size, void* d_ws, size_t ws_size,
                              hipStream_t stream) {
  const float* x  = (const float*)d_in[0];
  const float* W1 = (const float*)d_in[1];
  const float* b1 = (const float*)d_in[2];
  const float* W2 = (const float*)d_in[3];
  const float* b2 = (const float*)d_in[4];
  const float* Wg = (const float*)d_in[5];
  const float* bg = (const float*)d_in[6];

  float* outp = (float*)d_out;              // [1024*128]
  float* adj  = outp + NPT * D;             // [1024*1024]
  float* deg  = (float*)d_ws;               // [1024] f32
  unsigned short* xsw   = (unsigned short*)(deg + NPT);  // [1024*128] f16 swizzled
  unsigned short* w1p   = xsw + NPT * D;                 // [128*128] f16 frag-ordered
  unsigned short* xwghT = w1p + D * D;                   // [128*1024] f16

  k_prep<<<NPT, 128, 0, stream>>>(x, W1, Wg, outp, deg, xsw, w1p, xwghT);
  k_adj<<<dim3(256, 4), 256, 0, stream>>>(xsw, w1p, b1, W2, b2, adj, deg);
  k_d1<<<dim3(64, 4), 256, 0, stream>>>(adj, xwghT, deg, outp);
  k_d2<<<512, 256, 0, stream>>>(outp, deg, bg);
}

// Round 7
// 66.672 us; speedup vs baseline: 1.4554x; 1.0898x over previous
//
#include <hip/hip_runtime.h>
#include <hip/hip_bf16.h>
#include <math.h>

typedef __attribute__((ext_vector_type(8))) _Float16 half8;
typedef __attribute__((ext_vector_type(2))) _Float16 half2v;
typedef __attribute__((ext_vector_type(4))) float f32x4;
typedef __attribute__((ext_vector_type(4))) unsigned int u32x4;

#define NPT 1024
#define D   128

__device__ __forceinline__ unsigned int absdiff_pk(unsigned int a, unsigned int b) {
  half2v d = __builtin_bit_cast(half2v, a) - __builtin_bit_cast(half2v, b);
  return __builtin_bit_cast(unsigned int, d) & 0x7FFF7FFFu;
}

__device__ __forceinline__ unsigned int pk_max(unsigned int a, unsigned int b) {
  unsigned int r;
  asm("v_pk_max_f16 %0, %1, %2" : "=v"(r) : "v"(a), "v"(b));
  return r;
}

__device__ __forceinline__ unsigned int pkrtz(float lo, float hi) {
  return __builtin_bit_cast(unsigned int, __builtin_amdgcn_cvt_pkrtz(lo, hi));
}

__device__ __forceinline__ float fdot2(unsigned int a, unsigned int b, float c) {
  return __builtin_amdgcn_fdot2(__builtin_bit_cast(half2v, a),
                                __builtin_bit_cast(half2v, b), c, false);
}

// ---------------- kernel 1: prep ----------------
// xsw: swizzled f16 x: row i base i*256B, elem k at ((2k)^((i&7)<<4))
// w1p: fragment-ordered f16 W1: w1p[((k>>3)*128+hid)*8 + (k&7)] = W1[k][hid]
// xwghT: f16 [128 t][1024 i] transpose of x@Wg
__global__ __launch_bounds__(128) void k_prep(const float* __restrict__ x,
                                              const float* __restrict__ W1,
                                              const float* __restrict__ Wg,
                                              float* __restrict__ outp,
                                              float* __restrict__ deg,
                                              unsigned short* __restrict__ xsw,
                                              unsigned short* __restrict__ w1p,
                                              unsigned short* __restrict__ xwghT) {
  __shared__ float xi[D];
  const int i = blockIdx.x;
  const int t = threadIdx.x;
  const float xv = x[i * D + t];
  xi[t] = xv;
  outp[i * D + t] = 0.f;
  if (t == 0) deg[i] = 0.f;
  const _Float16 hv = (_Float16)xv;
  const int byte = i * 256 + ((2 * t) ^ ((i & 7) << 4));
  *(unsigned short*)((unsigned char*)xsw + byte) =
      __builtin_bit_cast(unsigned short, hv);
  if (i < 128) {  // t = k, i = hid
    const _Float16 wv = (_Float16)W1[t * 128 + i];
    w1p[((t >> 3) * 128 + i) * 8 + (t & 7)] = __builtin_bit_cast(unsigned short, wv);
  }
  __syncthreads();
  float acc = 0.f;
#pragma unroll 8
  for (int k = 0; k < D; ++k) acc += xi[k] * Wg[k * D + t];
  const _Float16 av = (_Float16)acc;
  xwghT[t * NPT + i] = __builtin_bit_cast(unsigned short, av);
}

// ---------------- kernel 2: adjacency, D[m=hid][n=j], no LDS, no barriers ----
// grid (256,2) x 256 thr. Wave = 1 i-row x 512 j (32 groups of 16).
// Full 128-hid W1 slice per wave (128 regs); j fragments per-lane from global.
__global__ __launch_bounds__(256, 2) void k_adj(const unsigned short* __restrict__ xsw,
                                                const unsigned short* __restrict__ w1p,
                                                const float* __restrict__ b1,
                                                const float* __restrict__ W2,
                                                const float* __restrict__ b2,
                                                float* __restrict__ adj,
                                                float* __restrict__ deg) {
  const int tid  = threadIdx.x;
  const int lane = tid & 63;
  const int w    = tid >> 6;   // 0..3
  const int l15  = lane & 15;
  const int g    = lane >> 4;  // 0..3
  const int i  = blockIdx.x * 4 + w;
  const int jq = blockIdx.y;   // 0..1, 512 j each

  // W1 -> regs: A[m=hid][k], hid = ht*16+l15, k = ks*32+g*8+e
  half8 w1f[4][8];
#pragma unroll
  for (int ks = 0; ks < 4; ++ks)
#pragma unroll
    for (int ht = 0; ht < 8; ++ht)
      w1f[ks][ht] = *(const half8*)(w1p + ((ks * 4 + g) * 128 + ht * 16 + l15) * 8);

  // relu(a+b1)*w2 = max(a,-b1)*w2 + b1*w2 : pack -b1, w2 as f16x2; c0 = sum b1*w2
  unsigned int nb1pk[8][2], w2pk[8][2];
  float c0 = 0.f;
#pragma unroll
  for (int ht = 0; ht < 8; ++ht) {
    const f32x4 bv = *(const f32x4*)&b1[ht * 16 + g * 4];
    const f32x4 wv = *(const f32x4*)&W2[ht * 16 + g * 4];
    c0 += bv[0] * wv[0] + bv[1] * wv[1] + bv[2] * wv[2] + bv[3] * wv[3];
    nb1pk[ht][0] = pkrtz(-bv[0], -bv[1]);
    nb1pk[ht][1] = pkrtz(-bv[2], -bv[3]);
    w2pk[ht][0] = pkrtz(wv[0], wv[1]);
    w2pk[ht][1] = pkrtz(wv[2], wv[3]);
  }
  c0 += __shfl_xor(c0, 16);
  c0 += __shfl_xor(c0, 32);
  const float B2 = b2[0] + c0;

  // xi fragments (broadcast row i)
  const unsigned char* xsb = (const unsigned char*)xsw;
  const unsigned char* xrow = xsb + i * 256;
  const int sxI = (i & 7) << 4;
  u32x4 xiu[4];
#pragma unroll
  for (int ks = 0; ks < 4; ++ks)
    xiu[ks] = *(const u32x4*)(xrow + ((ks * 64 + g * 16) ^ sxI));

  // per-lane j-row base: row = jq*512 + grp*16 + l15; (row&7)==(l15&7)
  const int sxJ = (l15 & 7) << 4;
  const unsigned char* jrow = xsb + (jq * 512 + l15) * 256;
  const int k0b = (0 * 64 + g * 16) ^ sxJ;
  const int k1b = (1 * 64 + g * 16) ^ sxJ;
  const int k2b = (2 * 64 + g * 16) ^ sxJ;
  const int k3b = (3 * 64 + g * 16) ^ sxJ;

  u32x4 jr0 = *(const u32x4*)(jrow + k0b);
  u32x4 jr1 = *(const u32x4*)(jrow + k1b);
  u32x4 jr2 = *(const u32x4*)(jrow + k2b);
  u32x4 jr3 = *(const u32x4*)(jrow + k3b);

  float degacc = 0.f;
#pragma unroll 1
  for (int grp = 0; grp < 32; ++grp) {
    const unsigned char* nrow = jrow + (grp + 1) * 4096;
    f32x4 acc[8];
#pragma unroll
    for (int ht = 0; ht < 8; ++ht) acc[ht] = f32x4{0.f, 0.f, 0.f, 0.f};

    __builtin_amdgcn_s_setprio(1);
    // ks = 0
    {
      u32x4 afu;
#pragma unroll
      for (int p = 0; p < 4; ++p) afu[p] = absdiff_pk(jr0[p], xiu[0][p]);
      if (grp < 31) jr0 = *(const u32x4*)(nrow + k0b);
      const half8 af = __builtin_bit_cast(half8, afu);
#pragma unroll
      for (int ht = 0; ht < 8; ++ht)
        acc[ht] = __builtin_amdgcn_mfma_f32_16x16x32_f16(w1f[0][ht], af, acc[ht], 0, 0, 0);
    }
    // ks = 1
    {
      u32x4 afu;
#pragma unroll
      for (int p = 0; p < 4; ++p) afu[p] = absdiff_pk(jr1[p], xiu[1][p]);
      if (grp < 31) jr1 = *(const u32x4*)(nrow + k1b);
      const half8 af = __builtin_bit_cast(half8, afu);
#pragma unroll
      for (int ht = 0; ht < 8; ++ht)
        acc[ht] = __builtin_amdgcn_mfma_f32_16x16x32_f16(w1f[1][ht], af, acc[ht], 0, 0, 0);
    }
    // ks = 2
    {
      u32x4 afu;
#pragma unroll
      for (int p = 0; p < 4; ++p) afu[p] = absdiff_pk(jr2[p], xiu[2][p]);
      if (grp < 31) jr2 = *(const u32x4*)(nrow + k2b);
      const half8 af = __builtin_bit_cast(half8, afu);
#pragma unroll
      for (int ht = 0; ht < 8; ++ht)
        acc[ht] = __builtin_amdgcn_mfma_f32_16x16x32_f16(w1f[2][ht], af, acc[ht], 0, 0, 0);
    }
    // ks = 3
    {
      u32x4 afu;
#pragma unroll
      for (int p = 0; p < 4; ++p) afu[p] = absdiff_pk(jr3[p], xiu[3][p]);
      if (grp < 31) jr3 = *(const u32x4*)(nrow + k3b);
      const half8 af = __builtin_bit_cast(half8, afu);
#pragma unroll
      for (int ht = 0; ht < 8; ++ht)
        acc[ht] = __builtin_amdgcn_mfma_f32_16x16x32_f16(w1f[3][ht], af, acc[ht], 0, 0, 0);
    }
    __builtin_amdgcn_s_setprio(0);

    // dot: 4 parallel fdot2 chains (depth 8 -> ~8), then tree-combine
    float s0 = 0.f, s1 = 0.f, s2 = 0.f, s3 = 0.f;
#pragma unroll
    for (int ht = 0; ht < 8; ht += 4) {
      unsigned int a0 = pk_max(pkrtz(acc[ht+0][0], acc[ht+0][1]), nb1pk[ht+0][0]);
      unsigned int b0 = pk_max(pkrtz(acc[ht+0][2], acc[ht+0][3]), nb1pk[ht+0][1]);
      unsigned int a1 = pk_max(pkrtz(acc[ht+1][0], acc[ht+1][1]), nb1pk[ht+1][0]);
      unsigned int b1x = pk_max(pkrtz(acc[ht+1][2], acc[ht+1][3]), nb1pk[ht+1][1]);
      unsigned int a2 = pk_max(pkrtz(acc[ht+2][0], acc[ht+2][1]), nb1pk[ht+2][0]);
      unsigned int b2x = pk_max(pkrtz(acc[ht+2][2], acc[ht+2][3]), nb1pk[ht+2][1]);
      unsigned int a3 = pk_max(pkrtz(acc[ht+3][0], acc[ht+3][1]), nb1pk[ht+3][0]);
      unsigned int b3 = pk_max(pkrtz(acc[ht+3][2], acc[ht+3][3]), nb1pk[ht+3][1]);
      s0 = fdot2(a0, w2pk[ht+0][0], s0);
      s1 = fdot2(a1, w2pk[ht+1][0], s1);
      s2 = fdot2(a2, w2pk[ht+2][0], s2);
      s3 = fdot2(a3, w2pk[ht+3][0], s3);
      s0 = fdot2(b0, w2pk[ht+0][1], s0);
      s1 = fdot2(b1x, w2pk[ht+1][1], s1);
      s2 = fdot2(b2x, w2pk[ht+2][1], s2);
      s3 = fdot2(b3, w2pk[ht+3][1], s3);
    }
    float s = (s0 + s1) + (s2 + s3);
    s += __shfl_xor(s, 16);
    s += __shfl_xor(s, 32);
    if (lane < 16) {
      const float sig = 1.f / (1.f + __expf(-(s + B2)));
      adj[i * NPT + jq * 512 + grp * 16 + l15] = sig;
      degacc += sig;
    }
  }
  if (lane < 16) {
#pragma unroll
    for (int m = 1; m <= 8; m <<= 1) degacc += __shfl_xor(degacc, m);
    if (l15 == 0) atomicAdd(&deg[i], degacc);
  }
}

// ---------------- kernel 3: out-partial via f16 MFMA, D[m=t][n=i] ----------
// out[t][i] += sum_j xwghT[t][j] * (adj[i][j]*dinv_j)   (adj symmetric)
__global__ __launch_bounds__(256) void k_d1(const float* __restrict__ adj,
                                            const unsigned short* __restrict__ xwghT,
                                            const float* __restrict__ deg,
                                            float* __restrict__ outp) {
  __shared__ unsigned short dv[256];
  const int tid  = threadIdx.x;
  const int lane = tid & 63;
  const int w    = tid >> 6;
  const int l15  = lane & 15;
  const int g    = lane >> 4;
  const int i0 = blockIdx.x * 16;
  const int jb = blockIdx.y * 256;

  const _Float16 dh = (_Float16)rsqrtf(deg[jb + tid]);
  dv[tid] = __builtin_bit_cast(unsigned short, dh);
  __syncthreads();

  f32x4 acc[2] = {f32x4{0,0,0,0}, f32x4{0,0,0,0}};
#pragma unroll
  for (int ks = 0; ks < 8; ++ks) {
    const int kofs = ks * 32 + g * 8;
    const f32x4 av0 = *(const f32x4*)&adj[(i0 + l15) * NPT + jb + kofs];
    const f32x4 av1 = *(const f32x4*)&adj[(i0 + l15) * NPT + jb + kofs + 4];
    const half2v* dq = (const half2v*)&dv[kofs];
    u32x4 bu;
    bu[0] = __builtin_bit_cast(unsigned int,
        half2v(__builtin_bit_cast(half2v, __builtin_amdgcn_cvt_pkrtz(av0[0], av0[1])) * dq[0]));
    bu[1] = __builtin_bit_cast(unsigned int,
        half2v(__builtin_bit_cast(half2v, __builtin_amdgcn_cvt_pkrtz(av0[2], av0[3])) * dq[1]));
    bu[2] = __builtin_bit_cast(unsigned int,
        half2v(__builtin_bit_cast(half2v, __builtin_amdgcn_cvt_pkrtz(av1[0], av1[1])) * dq[2]));
    bu[3] = __builtin_bit_cast(unsigned int,
        half2v(__builtin_bit_cast(half2v, __builtin_amdgcn_cvt_pkrtz(av1[2], av1[3])) * dq[3]));
    const half8 bf = __builtin_bit_cast(half8, bu);
#pragma unroll
    for (int tt = 0; tt < 2; ++tt) {
      const int trow = w * 32 + tt * 16 + l15;
      const half8 af = *(const half8*)(xwghT + trow * NPT + jb + kofs);
      acc[tt] = __builtin_amdgcn_mfma_f32_16x16x32_f16(af, bf, acc[tt], 0, 0, 0);
    }
  }
#pragma unroll
  for (int tt = 0; tt < 2; ++tt)
#pragma unroll
    for (int r = 0; r < 4; ++r)
      atomicAdd(&outp[(i0 + l15) * D + w * 32 + tt * 16 + g * 4 + r], acc[tt][r]);
}

// ---------------- kernel 4: out = leaky(rsqrt(deg_i) * partial + bg) --------
__global__ void k_d2(float* __restrict__ outp, const float* __restrict__ deg,
                     const float* __restrict__ bg) {
  const int idx = blockIdx.x * 256 + threadIdx.x;
  const int i = idx >> 7, t = idx & 127;
  const float v = outp[idx] * rsqrtf(deg[i]) + bg[t];
  outp[idx] = v > 0.f ? v : 0.2f * v;
}

extern "C" void kernel_launch(void* const* d_in, const int* in_sizes, int n_in,
                              void* d_out, int out_size, void* d_ws, size_t ws_size,
                              hipStream_t stream) {
  const float* x  = (const float*)d_in[0];
  const float* W1 = (const float*)d_in[1];
  const float* b1 = (const float*)d_in[2];
  const float* W2 = (const float*)d_in[3];
  const float* b2 = (const float*)d_in[4];
  const float* Wg = (const float*)d_in[5];
  const float* bg = (const float*)d_in[6];

  float* outp = (float*)d_out;              // [1024*128]
  float* adj  = outp + NPT * D;             // [1024*1024]
  float* deg  = (float*)d_ws;               // [1024] f32
  unsigned short* xsw   = (unsigned short*)(deg + NPT);  // [1024*128] f16 swizzled
  unsigned short* w1p   = xsw + NPT * D;                 // [128*128] f16 frag-ordered
  unsigned short* xwghT = w1p + D * D;                   // [128*1024] f16

  k_prep<<<NPT, 128, 0, stream>>>(x, W1, Wg, outp, deg, xsw, w1p, xwghT);
  k_adj<<<dim3(256, 2), 256, 0, stream>>>(xsw, w1p, b1, W2, b2, adj, deg);
  k_d1<<<dim3(64, 4), 256, 0, stream>>>(adj, xwghT, deg, outp);
  k_d2<<<512, 256, 0, stream>>>(outp, deg, bg);
}